// Round 18
// baseline (52.261 us; speedup 1.0000x reference)
//
#include <hip/hip_runtime.h>
#include <math.h>

#define B_ 512
#define C_ 100000
#define D_ 128
#define CT 128
#define NBLK ((C_ + CT - 1) / CT)   // 782 tiles
#define G_ NBLK
#define NSTEP (NBLK * 2)            // 1564 (tile, row-half) steps
#define MAIN_GRID 512
#define TILE_BYTES 33792            // 32768 bf16 payload + 1KB sidecar; NON-pow2 stride
#define NPAD 96                     // zero-filled tail cols in tile 781
#define LOG2E 1.4426950408889634f
#define K2S (2.0f * LOG2E)          // score_log2 = dot*K2S + K18S (norm folded in bf16)
#define K18S (-18.0f * LOG2E)
#define NPAIR_P (C_ / 2)            // 50000 proxy row-pairs
#define NPAIR_T (NPAIR_P + B_ / 2)  // + 256 batch row-pairs
#define CONV_BLOCKS 2048

typedef __attribute__((ext_vector_type(8))) short short8;  // 8 bf16 (MFMA A/B frag)
typedef __attribute__((ext_vector_type(4))) float f32x4;   // MFMA C/D frag

__device__ __forceinline__ unsigned short f2b(float x) {  // RNE f32->bf16
  union { float f; unsigned int i; } v; v.f = x;
  unsigned int r = v.i + 0x7FFFu + ((v.i >> 16) & 1u);
  return (unsigned short)(r >> 16);
}
__device__ __forceinline__ float b2f(unsigned short u) {
  union { float f; unsigned int i; } v; v.i = ((unsigned int)u) << 16; return v.f;
}

#if defined(__has_builtin)
#if __has_builtin(__builtin_amdgcn_exp2f)
#define EXP2F(x) __builtin_amdgcn_exp2f(x)
#endif
#endif
#ifndef EXP2F
#define EXP2F(x) __expf(0.69314718055994531f * (x))
#endif

// async global -> LDS, 16 B per lane; LDS dest = wave-uniform base + lane*16
__device__ __forceinline__ void gll16(const void* g, void* l) {
  __builtin_amdgcn_global_load_lds(
      (const __attribute__((address_space(1))) void*)g,
      (__attribute__((address_space(3))) void*)l, 16, 0, 0);
}

// --- kernel 1: pure-stream converter (R7-proven ~14us) ------------------------
// praw -> folded-norm bf16 swizzled tiles; batch -> xnb. Coalesced: one wave =
// 2 rows (64 lanes x float4). Sidecar (s2,qn) filled with constants.
__global__ __launch_bounds__(256) void convert_kernel(
    const float* __restrict__ praw, const float* __restrict__ batch,
    unsigned char* __restrict__ pb, unsigned short* __restrict__ xnb)
{
  int gid = blockIdx.x * 256 + threadIdx.x;
  // zero the 96 tail cols of tile 781 (payload bytes 8192..32767)
  if (gid < 3072) {
    ushort4 z = {0, 0, 0, 0};
    *(ushort4*)(pb + (size_t)(NBLK - 1) * TILE_BYTES + 8192 + gid * 8) = z;
  }
  // constant sidecar: s2 = K2S, qn = K18S for every tile col
  if (gid < NBLK * 128) {
    unsigned char* tp = pb + (size_t)(gid >> 7) * TILE_BYTES;
    int col = gid & 127;
    *(float*)(tp + 32768 + col * 4) = K2S;
    *(float*)(tp + 33280 + col * 4) = K18S;
  }
  const int lane = threadIdx.x & 63;
  const int wv   = threadIdx.x >> 6;
  const int f    = lane & 31;        // float4 index within the 512B row
  const int rh   = lane >> 5;        // which row of the pair
  const int nw   = CONV_BLOCKS * 4;
  for (int p = blockIdx.x * 4 + wv; p < NPAIR_T; p += nw) {
    const bool isp = (p < NPAIR_P);
    const int row = isp ? (p * 2 + rh) : ((p - NPAIR_P) * 2 + rh);
    const float4* src = isp ? (const float4*)praw : (const float4*)batch;
    float4 v = src[(size_t)row * 32 + f];
    float ss = v.x * v.x + v.y * v.y + v.z * v.z + v.w * v.w;
    ss += __shfl_xor(ss, 1);
    ss += __shfl_xor(ss, 2);
    ss += __shfl_xor(ss, 4);
    ss += __shfl_xor(ss, 8);
    ss += __shfl_xor(ss, 16);
    float sc = 3.0f * __frsqrt_rn(fmaxf(ss, 1e-24f));   // 3/||row||
    ushort4 o;
    o.x = f2b(v.x * sc); o.y = f2b(v.y * sc);
    o.z = f2b(v.z * sc); o.w = f2b(v.w * sc);
    if (isp) {
      int t = row >> 7, tcol = row & 127;
      int unit = tcol * 16 + ((f >> 1) ^ (tcol & 7));   // swizzled 16B slot
      *(ushort4*)(pb + (size_t)t * TILE_BYTES + unit * 16 + (f & 1) * 8) = o;
    } else {
      *(ushort4*)((unsigned char*)xnb + (size_t)row * 256 + f * 8) = o;
    }
  }
}

// --- kernel 2: persistent pipelined main (R6/R9 structure, 33792 stride) ------
// 512 blocks x 8 waves; XCD pair-swizzle: blocks bid and bid+8 share each tile
// and sit in the same XCD slot (bid&7) -> tile fetched once per XCD L2.
__global__ __launch_bounds__(512, 4) void pnca_main_kernel(
    const unsigned char* __restrict__ pb, const unsigned short* __restrict__ xnb,
    float* __restrict__ pt)
{
  __shared__ __align__(16) unsigned char lds[2][TILE_BYTES];

  const int tid  = threadIdx.x;
  const int lane = tid & 63;
  const int w    = tid >> 6;
  const int ll   = lane & 15;
  const int lq   = lane >> 4;

  // XCD pair swizzle: bid -> s0 such that halves of a pair are 8 bids apart
  const int bid = blockIdx.x;
  const int qq = bid >> 3, xx = bid & 7;
  int s = 2 * (xx + 8 * (qq >> 1)) + (qq & 1);   // bijection on [0,512)

  const int half  = s & 1;                        // preserved by s += 512
  const int rbase = half * 256 + w * 32;

  // A fragments: this wave's 32 rows of xnb (L2-hot), constant across steps
  short8 a[2][4];
#pragma unroll
  for (int m = 0; m < 2; ++m)
#pragma unroll
    for (int ks = 0; ks < 4; ++ks)
      a[m][ks] = *(const short8*)(xnb + (size_t)(rbase + m * 16 + ll) * D_ + ks * 32 + lq * 8);
  asm volatile("s_waitcnt vmcnt(0)" ::: "memory");   // vmcnt tracks gll16 only

  // prologue: stage step s into buf 0 (4 payload + 1 sidecar gll16)
  {
    const unsigned char* tp = pb + (size_t)(s >> 1) * TILE_BYTES;
#pragma unroll
    for (int k = 0; k < 4; ++k)
      gll16(tp + (size_t)((w * 4 + k) * 64 + lane) * 16, &lds[0][(w * 4 + k) * 1024]);
    gll16(tp + 32768 + lane * 16, &lds[0][32768]);   // s2+qn sidecar
  }

  int p = 0;
  while (true) {
    const int snext = s + MAIN_GRID;
    const bool hasnext = (snext < NSTEP);
    if (hasnext) {
      const unsigned char* tp = pb + (size_t)(snext >> 1) * TILE_BYTES;
#pragma unroll
      for (int k = 0; k < 4; ++k)
        gll16(tp + (size_t)((w * 4 + k) * 64 + lane) * 16, &lds[p ^ 1][(w * 4 + k) * 1024]);
      gll16(tp + 32768 + lane * 16, &lds[p ^ 1][32768]);
      asm volatile("s_waitcnt vmcnt(5)" ::: "memory");  // buf[p] done; next 5 in flight
    } else {
      asm volatile("s_waitcnt vmcnt(0)" ::: "memory");
    }
    __builtin_amdgcn_s_barrier();
    __builtin_amdgcn_sched_barrier(0);

    const unsigned char* buf = lds[p];
    const float* sq = (const float*)(buf + 32768);
    float part[2][4] = {{0.f, 0.f, 0.f, 0.f}, {0.f, 0.f, 0.f, 0.f}};
#pragma unroll
    for (int g = 0; g < 8; ++g) {
      const int colg = g * 16 + ll;
      const float s2v = sq[colg];
      const float qnv = sq[128 + colg];
      short8 bfr[4];
#pragma unroll
      for (int ks = 0; ks < 4; ++ks)
        bfr[ks] = *(const short8*)(buf + (size_t)(colg * 16 + ((ks * 4 + lq) ^ (colg & 7))) * 16);
      f32x4 acc0 = (f32x4){0.f, 0.f, 0.f, 0.f};
      f32x4 acc1 = (f32x4){0.f, 0.f, 0.f, 0.f};
#pragma unroll
      for (int ks = 0; ks < 4; ++ks) {
        acc0 = __builtin_amdgcn_mfma_f32_16x16x32_bf16(a[0][ks], bfr[ks], acc0, 0, 0, 0);
        acc1 = __builtin_amdgcn_mfma_f32_16x16x32_bf16(a[1][ks], bfr[ks], acc1, 0, 0, 0);
      }
#pragma unroll
      for (int r = 0; r < 4; ++r) {
        part[0][r] += EXP2F(fmaf(acc0[r], s2v, qnv));
        part[1][r] += EXP2F(fmaf(acc1[r], s2v, qnv));
      }
    }
    // 16-lane reduce, write partials; C/D layout: col=ll, row=lq*4+r
#pragma unroll
    for (int m = 0; m < 2; ++m)
#pragma unroll
      for (int r = 0; r < 4; ++r) {
        float v = part[m][r];
        v += __shfl_xor(v, 1);
        v += __shfl_xor(v, 2);
        v += __shfl_xor(v, 4);
        v += __shfl_xor(v, 8);
        if (ll == 0)
          pt[(size_t)(s >> 1) * B_ + rbase + m * 16 + lq * 4 + r] = v;
      }
    __builtin_amdgcn_s_barrier();   // buf[p] reads done before it is re-staged
    if (!hasnext) break;
    s = snext;
    p ^= 1;
  }
}

// --- kernel 3: per-row combine + positive distance + loss ---------------------
__global__ __launch_bounds__(256) void finalize_rows_kernel(
    const float* __restrict__ praw, const unsigned short* __restrict__ xnb,
    const int* __restrict__ labels, const float* __restrict__ pt,
    float* __restrict__ lossb)
{
  int lane = threadIdx.x & 63, wv = threadIdx.x >> 6;
  int row = blockIdx.x * 4 + wv;             // grid=128 -> 512 rows
  int lab = labels[row];
  float2 pv = *(const float2*)(praw + (size_t)lab * D_ + lane * 2);
  ushort2 xv = *(const ushort2*)(xnb + (size_t)row * D_ + lane * 2);
  float xa = b2f(xv.x), xb = b2f(xv.y);
  float ssp = pv.x * pv.x + pv.y * pv.y;
  float dp  = xa * pv.x + xb * pv.y;
#pragma unroll
  for (int off = 32; off; off >>= 1) {
    ssp += __shfl_xor(ssp, off);
    dp  += __shfl_xor(dp, off);
  }
  float pd = 18.f - 2.f * dp * (3.f / fmaxf(sqrtf(ssp), 1e-12f));  // positive dist
  float s = 0.f;
  for (int gg = lane; gg < G_; gg += 64) s += pt[(size_t)gg * B_ + row];
#pragma unroll
  for (int off = 32; off; off >>= 1) s += __shfl_xor(s, off);
  if (lane == 0) {
    const float tail = (float)NPAD * EXP2F(K18S);   // zero-filled cols' exact sum
    lossb[row] = pd + logf(s - __expf(-pd) - tail);
  }
}

// --- kernel 4: mean over 512 rows ---------------------------------------------
__global__ __launch_bounds__(512) void reduce_mean_kernel(
    const float* __restrict__ lossb, float* __restrict__ out)
{
  int t = threadIdx.x;
  float v = lossb[t];
#pragma unroll
  for (int off = 1; off < 64; off <<= 1) v += __shfl_xor(v, off);
  __shared__ float red[8];
  if ((t & 63) == 0) red[t >> 6] = v;
  __syncthreads();
  if (t == 0) {
    float tot = 0.f;
    for (int i = 0; i < 8; ++i) tot += red[i];
    out[0] = tot / (float)B_;
  }
}

extern "C" void kernel_launch(void* const* d_in, const int* in_sizes, int n_in,
                              void* d_out, int out_size, void* d_ws, size_t ws_size,
                              hipStream_t stream)
{
  const float* batch   = (const float*)d_in[0];
  const int*   labels  = (const int*)d_in[1];
  const float* proxies = (const float*)d_in[2];
  float* out = (float*)d_out;

  unsigned char* ws = (unsigned char*)d_ws;
  unsigned short* xnb = (unsigned short*)ws;                          // 128 KB
  unsigned char*  pb  = ws + 131072;                                  // 782*33792 ~= 26.4 MB
  float* pt    = (float*)(ws + 131072 + (size_t)NBLK * TILE_BYTES);   // ~1.6 MB
  float* lossb = (float*)(ws + 131072 + (size_t)NBLK * TILE_BYTES
                          + (size_t)G_ * B_ * 4);                     // 2 KB

  convert_kernel<<<CONV_BLOCKS, 256, 0, stream>>>(proxies, batch, pb, xnb);
  pnca_main_kernel<<<MAIN_GRID, 512, 0, stream>>>(pb, xnb, pt);
  finalize_rows_kernel<<<B_ / 4, 256, 0, stream>>>(proxies, xnb, labels, pt, lossb);
  reduce_mean_kernel<<<1, 512, 0, stream>>>(lossb, out);
}